// Round 3
// baseline (1178.106 us; speedup 1.0000x reference)
//
#include <hip/hip_runtime.h>

typedef _Float16 half2_t __attribute__((ext_vector_type(2)));
typedef unsigned int uint32;

#if __has_builtin(__builtin_amdgcn_fdot2)
#define FDOT2(a, b, c) __builtin_amdgcn_fdot2((a), (b), (c), false)
#else
__device__ __forceinline__ float FDOT2(half2_t a, half2_t b, float c) {
    return c + (float)a.x * (float)b.x + (float)a.y * (float)b.y;
}
#endif

__device__ __forceinline__ half2_t h2_from_bits(uint32 b) {
    union { uint32 u; half2_t h; } c; c.u = b; return c.h;
}

namespace {
constexpr int D  = 48;
constexpr int D4 = 24;
constexpr int S2 = D * D4;        // 1152
constexpr int S1 = D * S2;        // 55296
constexpr int SC = D * S1;        // 2654208 elems per channel volume
constexpr int NB = 2;
constexpr int NELEM = NB * 3 * SC;
constexpr int NPAIR_H2 = NB * 3 * SC;   // half2 elements in the pairs buffer
constexpr int NS = NB * D * D * D;      // 221184 spatial lines
}

// ---------------- pack kernels (run once per launch, tiny/BW-bound) ----------

__global__ __launch_bounds__(256) void pack_weights(
        const float* __restrict__ Wg, half2_t* __restrict__ pw)
{
    int i = blockIdx.x * 256 + threadIdx.x;
    const int NTOT = 4 * 3 * 27 * 9;          // 2916
    if (i >= NTOT) return;
    int k4 = i % 3; int r = i / 3;
    int co = r % 3; r /= 3;
    int k123 = r % 27; r /= 27;
    int p = r % 3; int l = r / 3;
    int ciA = 2 * p, ciB = 2 * p + 1;
    float a = Wg[((l * 3 + co) * 6 + ciA) * 81 + k123 * 3 + k4];
    float b = Wg[((l * 3 + co) * 6 + ciB) * 81 + k123 * 3 + k4];
    pw[i] = half2_t{(_Float16)a, (_Float16)b};
}

__global__ __launch_bounds__(256) void pack_init(
        const float* __restrict__ f, const float* __restrict__ bnd,
        half2_t* __restrict__ pairs)
{
    int i = blockIdx.x * 256 + threadIdx.x;   // each thread packs 4 consecutive z
    int plane = i / (SC / 4);
    int zz = (i % (SC / 4)) * 4;
    int b = plane / 3, p = plane % 3;
    const float* A; const float* Bc;
    if (p == 0)      { A = f   + (size_t)(b*3 + 0) * SC; Bc = f   + (size_t)(b*3 + 1) * SC; }
    else if (p == 1) { A = f   + (size_t)(b*3 + 2) * SC; Bc = bnd + (size_t)(b*3 + 0) * SC; }
    else             { A = bnd + (size_t)(b*3 + 1) * SC; Bc = bnd + (size_t)(b*3 + 2) * SC; }
    float4 a = *(const float4*)(A + zz);
    float4 c = *(const float4*)(Bc + zz);
    union { float4 f4; half2_t h[4]; } u;
    u.h[0] = half2_t{(_Float16)a.x, (_Float16)c.x};
    u.h[1] = half2_t{(_Float16)a.y, (_Float16)c.y};
    u.h[2] = half2_t{(_Float16)a.z, (_Float16)c.z};
    u.h[3] = half2_t{(_Float16)a.w, (_Float16)c.w};
    *(float4*)(pairs + (size_t)plane * SC + zz) = u.f4;
}

// ---------------- Stage A: gather conv via v_pk_fma_f16 ----------------------
// Lane-interleaved j-split (thread t: line t>>1, half H = t&1), unchanged
// addressing. MAC pipe switched from v_dot2_f32_f16 (2 MACs / 4 cyc, f32-rate)
// to v_pk_fma_f16 (2 MACs / 2 cyc, the 2x f16 vector rate): channel-paired
// f16x2 partial accumulators p0 (k4-tap 0) and p1 (taps 1,2), folded into the
// f32 master accumulator once per (p,k1) group (<=27 f16 adds per partial
// lane) via one dot2 against (1,1).

__global__ __launch_bounds__(256, 3) void convA(
        const half2_t* __restrict__ pairs, const half2_t* __restrict__ pw,
        const float* __restrict__ bg, _Float16* __restrict__ dst)
{
    int t = blockIdx.x * 256 + threadIdx.x;
    int H = t & 1;
    int s = t >> 1;
    int x3 = s % D; int r = s / D;
    int x2 = r % D; r /= D;
    int x1 = r % D; int b = r / D;

    const uint32 maskL = H ? 0xFFFFFFFFu : 0u;   // W[0] live only for H=1
    const uint32 maskR = ~maskL;                  // W[13] live only for H=0
    const int bodyOff = 12 * H;                   // half2 units
    const int edgeOff = 12 - H;                   // half2 units

    const half2_t hzero = half2_t{(_Float16)0, (_Float16)0};
    const half2_t hone  = half2_t{(_Float16)1, (_Float16)1};

    float acc[3][12];
    half2_t p0[3][12], p1[3][12];
#pragma unroll
    for (int c = 0; c < 3; ++c) {
        float bb = bg[c];
#pragma unroll
        for (int j = 0; j < 12; ++j) {
            acc[c][j] = bb;
            p0[c][j] = hzero;
            p1[c][j] = hzero;
        }
    }

#pragma unroll 1
    for (int p = 0; p < 3; ++p) {
        const half2_t* src = pairs + (size_t)(b*3 + p) * SC;
#pragma unroll 1
        for (int k1 = 0; k1 < 3; ++k1) {
            int z1 = x1 + k1 - 1;
            if ((unsigned)z1 >= (unsigned)D) continue;
            const half2_t* src1 = src + z1 * S1;
#pragma unroll
            for (int k2 = 0; k2 < 3; ++k2) {
                int z2 = x2 + k2 - 1;
                if ((unsigned)z2 >= (unsigned)D) continue;
#pragma unroll
                for (int k3 = 0; k3 < 3; ++k3) {
                    int z3 = x3 + k3 - 1;
                    if ((unsigned)z3 >= (unsigned)D) continue;
                    const half2_t* lb = src1 + z2 * S2 + z3 * D4;
                    union { float4 f4[3]; half2_t h[12]; } B;
                    const float4* L4 = (const float4*)(lb + bodyOff);
                    B.f4[0] = L4[0]; B.f4[1] = L4[1]; B.f4[2] = L4[2];
                    uint32 ev = *(const uint32*)(lb + edgeOff);

                    half2_t W[14];
                    W[0]  = h2_from_bits(ev & maskL);
#pragma unroll
                    for (int i = 0; i < 12; ++i) W[1 + i] = B.h[i];
                    W[13] = h2_from_bits(ev & maskR);

                    const half2_t* w = pw + (size_t)((p * 27 + (k1*9 + k2*3 + k3)) * 9);
#pragma unroll
                    for (int co = 0; co < 3; ++co) {
                        half2_t w0 = w[co*3 + 0];
                        half2_t w1 = w[co*3 + 1];
                        half2_t w2 = w[co*3 + 2];
#pragma unroll
                        for (int j = 0; j < 12; ++j) {
                            p0[co][j] = w0 * W[j]     + p0[co][j];   // v_pk_fma_f16
                            p1[co][j] = w1 * W[j + 1] + p1[co][j];
                            p1[co][j] = w2 * W[j + 2] + p1[co][j];
                        }
                    }
                }
            }
            // fold this (p,k1) group's f16 partials into the f32 master
#pragma unroll
            for (int co = 0; co < 3; ++co) {
#pragma unroll
                for (int j = 0; j < 12; ++j) {
                    half2_t sf = p0[co][j] + p1[co][j];      // v_pk_add_f16
                    acc[co][j] = FDOT2(sf, hone, acc[co][j]); // acc += sf.x + sf.y
                    p0[co][j] = hzero;
                    p1[co][j] = hzero;
                }
            }
        }
    }

    int spos = x1 * S1 + x2 * S2 + x3 * D4 + 12 * H;
#pragma unroll
    for (int co = 0; co < 3; ++co) {
        union { float2 f2[3]; _Float16 h[12]; } u;
#pragma unroll
        for (int j = 0; j < 12; ++j) u.h[j] = (_Float16)acc[co][j];
        float2* o2 = (float2*)(dst + (b*3 + co) * (size_t)SC + spos);
#pragma unroll
        for (int q = 0; q < 3; ++q) o2[q] = u.f2[q];
    }
}

// ---------------- Stage B+C fused, lane-interleaved j-split ------------------
// Unchanged math; k1 loop now fully unrolled so all 27 taps' global loads can
// software-pipeline (convBC is load-latency-bound: est. VALUBusy ~30%).

__global__ __launch_bounds__(256, 3) void convBC(
        const _Float16* __restrict__ t1, half2_t* pairs,
        const float* __restrict__ W1, const float* __restrict__ b1,
        const float* __restrict__ W2, const float* __restrict__ b2,
        const float* __restrict__ Wd, const float* __restrict__ bd,
        float* __restrict__ dstF32, int writeF32)
{
    int t = blockIdx.x * 256 + threadIdx.x;
    int H = t & 1;
    int s = t >> 1;
    int x3 = s % D; int r = s / D;
    int x2 = r % D; r /= D;
    int x1 = r % D; int b = r / D;
    const bool isH1 = (H != 0);

    int spos = x1 * S1 + x2 * S2 + x3 * D4;
    const int bodyOff = 12 * H;       // f16 units
    const int edgeOff = 12 - H;       // f16 units

    float t2l[3][14];
#pragma unroll
    for (int c = 0; c < 3; ++c) {
        float bb = b1[c];
        t2l[c][0]  = isH1 ? bb : 0.f;
        t2l[c][13] = isH1 ? 0.f : bb;
#pragma unroll
        for (int m = 1; m < 13; ++m) t2l[c][m] = bb;
    }

#pragma unroll 1
    for (int ci = 0; ci < 3; ++ci) {
        const _Float16* src = t1 + (b*3 + ci) * (size_t)SC;
#pragma unroll
        for (int k1 = 0; k1 < 3; ++k1) {
            int z1 = x1 + k1 - 1;
            if ((unsigned)z1 >= (unsigned)D) continue;
            const _Float16* src1 = src + z1 * S1;
#pragma unroll
            for (int k2 = 0; k2 < 3; ++k2) {
                int z2 = x2 + k2 - 1;
                if ((unsigned)z2 >= (unsigned)D) continue;
#pragma unroll
                for (int k3 = 0; k3 < 3; ++k3) {
                    int z3 = x3 + k3 - 1;
                    if ((unsigned)z3 >= (unsigned)D) continue;
                    const _Float16* lb = src1 + z2 * S2 + z3 * D4;
                    union { float2 f2[3]; half2_t h[6]; } Bd;
                    const float2* L2 = (const float2*)(lb + bodyOff);
                    Bd.f2[0] = L2[0]; Bd.f2[1] = L2[1]; Bd.f2[2] = L2[2];
                    _Float16 eh = lb[edgeOff];
                    float ef = (float)eh;

                    float v[14];
                    v[0]  = isH1 ? ef : 0.f;
                    v[13] = isH1 ? 0.f : ef;
#pragma unroll
                    for (int i = 0; i < 6; ++i) {
                        v[1 + 2*i] = (float)Bd.h[i].x;
                        v[2 + 2*i] = (float)Bd.h[i].y;
                    }
                    int kk = k1*9 + k2*3 + k3;
                    float wA = W1[  0 + ci*27 + kk];
                    float wB = W1[ 81 + ci*27 + kk];
                    float wC = W1[162 + ci*27 + kk];
#pragma unroll
                    for (int m = 0; m < 14; ++m) {
                        t2l[0][m] += wA * v[m];
                        t2l[1][m] += wB * v[m];
                        t2l[2][m] += wC * v[m];
                    }
                }
            }
        }
    }

    // residual source + bnd0 passthrough from pairs (this lane's 12-wide chunk)
    half2_t* p0ptr = pairs + (size_t)(b*3 + 0) * SC + spos + 12*H;
    half2_t* p1ptr = pairs + (size_t)(b*3 + 1) * SC + spos + 12*H;
    half2_t rp0[12], rp1[12];
#pragma unroll
    for (int q = 0; q < 3; ++q) {
        union { float4 f4; half2_t h[4]; } u;
        u.f4 = ((const float4*)p0ptr)[q];
        rp0[4*q+0]=u.h[0]; rp0[4*q+1]=u.h[1]; rp0[4*q+2]=u.h[2]; rp0[4*q+3]=u.h[3];
        u.f4 = ((const float4*)p1ptr)[q];
        rp1[4*q+0]=u.h[0]; rp1[4*q+1]=u.h[1]; rp1[4*q+2]=u.h[2]; rp1[4*q+3]=u.h[3];
    }

    float U[3][3][3];
#pragma unroll
    for (int co = 0; co < 3; ++co)
#pragma unroll
        for (int ci = 0; ci < 3; ++ci)
#pragma unroll
            for (int k = 0; k < 3; ++k)
                U[co][ci][k] = W2[co*9 + ci*3 + k];
    float WD[9];
#pragma unroll
    for (int i = 0; i < 9; ++i) WD[i] = Wd[i];
    float c0 = b2[0] + bd[0], c1 = b2[1] + bd[1], c2 = b2[2] + bd[2];

    float o0[12], o1[12], o2[12];
#pragma unroll
    for (int n = 0; n < 12; ++n) {
        float s0 = c0, s1 = c1, s2 = c2;
#pragma unroll
        for (int ci = 0; ci < 3; ++ci) {
            float tm = t2l[ci][n + 0];
            float tc = t2l[ci][n + 1];
            float tp = t2l[ci][n + 2];
            s0 += U[0][ci][0]*tm + U[0][ci][1]*tc + U[0][ci][2]*tp;
            s1 += U[1][ci][0]*tm + U[1][ci][1]*tc + U[1][ci][2]*tp;
            s2 += U[2][ci][0]*tm + U[2][ci][1]*tc + U[2][ci][2]*tp;
        }
        float pv0 = (float)rp0[n].x, pv1 = (float)rp0[n].y, pv2 = (float)rp1[n].x;
        s0 += WD[0]*pv0 + WD[1]*pv1 + WD[2]*pv2;
        s1 += WD[3]*pv0 + WD[4]*pv1 + WD[5]*pv2;
        s2 += WD[6]*pv0 + WD[7]*pv1 + WD[8]*pv2;
        o0[n] = s0; o1[n] = s1; o2[n] = s2;
    }

    // vectorized pair stores: plane0 = (o0,o1), plane1 = (o2, bnd0 passthrough)
    {
        union { float4 f4[3]; half2_t h[12]; } u0, u1;
#pragma unroll
        for (int n = 0; n < 12; ++n) {
            u0.h[n] = half2_t{(_Float16)o0[n], (_Float16)o1[n]};
            u1.h[n] = half2_t{(_Float16)o2[n], rp1[n].y};
        }
#pragma unroll
        for (int q = 0; q < 3; ++q) {
            ((float4*)p0ptr)[q] = u0.f4[q];
            ((float4*)p1ptr)[q] = u1.f4[q];
        }
    }

    if (writeF32) {
        float* d0 = dstF32 + (size_t)(b*3 + 0) * SC + spos + 12*H;
        float* d1 = dstF32 + (size_t)(b*3 + 1) * SC + spos + 12*H;
        float* d2 = dstF32 + (size_t)(b*3 + 2) * SC + spos + 12*H;
#pragma unroll
        for (int q = 0; q < 3; ++q) {
            ((float4*)d0)[q] = make_float4(o0[4*q], o0[4*q+1], o0[4*q+2], o0[4*q+3]);
            ((float4*)d1)[q] = make_float4(o1[4*q], o1[4*q+1], o1[4*q+2], o1[4*q+3]);
            ((float4*)d2)[q] = make_float4(o2[4*q], o2[4*q+1], o2[4*q+2], o2[4*q+3]);
        }
    }
}

extern "C" void kernel_launch(void* const* d_in, const int* in_sizes, int n_in,
                              void* d_out, int out_size, void* d_ws, size_t ws_size,
                              hipStream_t stream)
{
    const float* f   = (const float*)d_in[0];
    const float* bnd = (const float*)d_in[1];
    const float* Wg  = (const float*)d_in[2];
    const float* bg  = (const float*)d_in[3];
    const float* W1  = (const float*)d_in[4];
    const float* b1  = (const float*)d_in[5];
    const float* W2  = (const float*)d_in[6];
    const float* b2  = (const float*)d_in[7];
    const float* Wd  = (const float*)d_in[8];
    const float* bd  = (const float*)d_in[9];

    _Float16* t1h   = (_Float16*)d_ws;                   // 32 MB f16
    half2_t*  pairs = (half2_t*)(t1h + NELEM);           // 64 MB f16 pairs
    half2_t*  pw    = pairs + NPAIR_H2;                  // 11.7 KB packed weights

    pack_weights<<<dim3((2916 + 255) / 256), dim3(256), 0, stream>>>(Wg, pw);
    pack_init<<<dim3(NB * 3 * (SC / 4) / 256), dim3(256), 0, stream>>>(f, bnd, pairs);

    const int grid = 2 * NS / 256;   // 1728 blocks; lane pairs share a line
    for (int l = 0; l < 4; ++l) {
        convA<<<dim3(grid), dim3(256), 0, stream>>>(pairs, pw + l * 729, bg + l*3, t1h);
        convBC<<<dim3(grid), dim3(256), 0, stream>>>(
            t1h, pairs, W1 + l*243, b1 + l*3, W2 + l*27, b2 + l*3,
            Wd + l*9, bd + l*3, (float*)d_out, l == 3 ? 1 : 0);
    }
}

// Round 4
// 1052.761 us; speedup vs baseline: 1.1191x; 1.1191x over previous
//
#include <hip/hip_runtime.h>

typedef _Float16 half2_t __attribute__((ext_vector_type(2)));
typedef unsigned int uint32;

#if __has_builtin(__builtin_amdgcn_fdot2)
#define FDOT2(a, b, c) __builtin_amdgcn_fdot2((a), (b), (c), false)
#else
__device__ __forceinline__ float FDOT2(half2_t a, half2_t b, float c) {
    return c + (float)a.x * (float)b.x + (float)a.y * (float)b.y;
}
#endif

__device__ __forceinline__ half2_t h2_from_bits(uint32 b) {
    union { uint32 u; half2_t h; } c; c.u = b; return c.h;
}

namespace {
constexpr int D  = 48;
constexpr int D4 = 24;
constexpr int S2 = D * D4;        // 1152
constexpr int S1 = D * S2;        // 55296
constexpr int SC = D * S1;        // 2654208 elems per channel volume
constexpr int NB = 2;
constexpr int NELEM = NB * 3 * SC;
constexpr int NPAIR_H2 = NB * 3 * SC;   // half2 elements in the pairs buffer
constexpr int NS = NB * D * D * D;      // 221184 spatial lines

// convA tile geometry
constexpr int T1 = 8, T2 = 4, T3 = 4;             // lines per tile: 128
constexpr int HL1 = T1 + 2, HL2 = T2 + 2, HL3 = T3 + 2;   // staged 10x6x6
constexpr int NLINE = HL1 * HL2 * HL3;            // 360
constexpr int LSTR  = 28;                          // half2 words/line (24 + 4 pad)
constexpr int NT1 = D / T1, NT2 = D / T2, NT3 = D / T3;   // 6,12,12
constexpr int TILES = NT1 * NT2 * NT3;            // 864 per batch
}

// ---------------- pack kernels (run once per launch, tiny/BW-bound) ----------

__global__ __launch_bounds__(256) void pack_weights(
        const float* __restrict__ Wg, half2_t* __restrict__ pw)
{
    int i = blockIdx.x * 256 + threadIdx.x;
    const int NTOT = 4 * 3 * 27 * 9;          // 2916
    if (i >= NTOT) return;
    int k4 = i % 3; int r = i / 3;
    int co = r % 3; r /= 3;
    int k123 = r % 27; r /= 27;
    int p = r % 3; int l = r / 3;
    int ciA = 2 * p, ciB = 2 * p + 1;
    float a = Wg[((l * 3 + co) * 6 + ciA) * 81 + k123 * 3 + k4];
    float b = Wg[((l * 3 + co) * 6 + ciB) * 81 + k123 * 3 + k4];
    pw[i] = half2_t{(_Float16)a, (_Float16)b};
}

__global__ __launch_bounds__(256) void pack_init(
        const float* __restrict__ f, const float* __restrict__ bnd,
        half2_t* __restrict__ pairs)
{
    int i = blockIdx.x * 256 + threadIdx.x;   // each thread packs 4 consecutive z
    int plane = i / (SC / 4);
    int zz = (i % (SC / 4)) * 4;
    int b = plane / 3, p = plane % 3;
    const float* A; const float* Bc;
    if (p == 0)      { A = f   + (size_t)(b*3 + 0) * SC; Bc = f   + (size_t)(b*3 + 1) * SC; }
    else if (p == 1) { A = f   + (size_t)(b*3 + 2) * SC; Bc = bnd + (size_t)(b*3 + 0) * SC; }
    else             { A = bnd + (size_t)(b*3 + 1) * SC; Bc = bnd + (size_t)(b*3 + 2) * SC; }
    float4 a = *(const float4*)(A + zz);
    float4 c = *(const float4*)(Bc + zz);
    union { float4 f4; half2_t h[4]; } u;
    u.h[0] = half2_t{(_Float16)a.x, (_Float16)c.x};
    u.h[1] = half2_t{(_Float16)a.y, (_Float16)c.y};
    u.h[2] = half2_t{(_Float16)a.z, (_Float16)c.z};
    u.h[3] = half2_t{(_Float16)a.w, (_Float16)c.w};
    *(float4*)(pairs + (size_t)plane * SC + zz) = u.f4;
}

// ---------------- Stage A: LDS-tiled gather conv -----------------------------
// Block = (8,4,4)-line tile x 2 H-halves = 256 threads. Per input plane p:
// cooperatively stage the (10,6,6)-line halo window into LDS (OOB lines
// zero-filled -> zero-pad conv semantics with NO per-tap bounds checks),
// barrier, then all 27 taps read ds_read_b128 at compile-time offsets.
// MAC pipe: v_dot2_f32_f16 (R3 established pk_fma_f16 is same-rate; reverted).

__global__ __launch_bounds__(256, 4) void convA(
        const half2_t* __restrict__ pairs, const half2_t* __restrict__ pw,
        const float* __restrict__ bg, _Float16* __restrict__ dst)
{
    __shared__ half2_t lds[NLINE * LSTR];      // 40320 B

    int tid = threadIdx.x;
    int H  = tid & 1;
    int li = tid >> 1;                 // 0..127
    int l3 = li & 3;
    int l2 = (li >> 2) & 3;
    int l1 = li >> 4;                  // 0..7

    int bid = blockIdx.x;
    int b   = bid / TILES;
    int rr  = bid % TILES;
    int t1i = rr / (NT2 * NT3);
    int t2i = (rr / NT3) % NT2;
    int t3i = rr % NT3;

    int x1 = t1i * T1 + l1;
    int x2 = t2i * T2 + l2;
    int x3 = t3i * T3 + l3;

    const uint32 maskL = H ? 0xFFFFFFFFu : 0u;   // W[0] live only for H=1
    const uint32 maskR = ~maskL;                  // W[13] live only for H=0

    float acc[3][12];
#pragma unroll
    for (int c = 0; c < 3; ++c) {
        float bb = bg[c];
#pragma unroll
        for (int j = 0; j < 12; ++j) acc[c][j] = bb;
    }

    // line index within LDS for tap (0,0,0); tap offset is a compile-time const
    const int baseline = (l1 * HL2 + l2) * HL3 + l3;
    const half2_t* lbase = &lds[baseline * LSTR];

#pragma unroll 1
    for (int p = 0; p < 3; ++p) {
        if (p) __syncthreads();        // protect previous plane's readers
        // ---- stage plane p: 360 lines x 6 float4 = 2160 units ----
        {
            const half2_t* src = pairs + (size_t)(b*3 + p) * SC;
            for (int i = tid; i < NLINE * 6; i += 256) {
                int q = i % 6; int line = i / 6;
                int s3 = line % HL3;
                int s2 = (line / HL3) % HL2;
                int s1 = line / (HL2 * HL3);
                int z1 = t1i * T1 - 1 + s1;
                int z2 = t2i * T2 - 1 + s2;
                int z3 = t3i * T3 - 1 + s3;
                float4 val = make_float4(0.f, 0.f, 0.f, 0.f);
                if ((unsigned)z1 < (unsigned)D && (unsigned)z2 < (unsigned)D &&
                    (unsigned)z3 < (unsigned)D)
                    val = *(const float4*)(src + (size_t)z1*S1 + z2*S2 + z3*D4 + q*4);
                *(float4*)(&lds[line * LSTR + q * 4]) = val;
            }
        }
        __syncthreads();

        const half2_t* pwp = pw + (size_t)p * 243;   // (p*27 + k123)*9
#pragma unroll
        for (int k1 = 0; k1 < 3; ++k1) {
#pragma unroll
            for (int k2 = 0; k2 < 3; ++k2) {
#pragma unroll
                for (int k3 = 0; k3 < 3; ++k3) {
                    const half2_t* lb = lbase +
                        (k1 * (HL2*HL3) + k2 * HL3 + k3) * LSTR;
                    union { float4 f4[3]; half2_t h[12]; } B;
                    const float4* L4 = (const float4*)(lb + 12 * H);
                    B.f4[0] = L4[0]; B.f4[1] = L4[1]; B.f4[2] = L4[2];
                    uint32 ev = *(const uint32*)(lb + (12 - H));

                    half2_t W[14];
                    W[0]  = h2_from_bits(ev & maskL);
#pragma unroll
                    for (int i = 0; i < 12; ++i) W[1 + i] = B.h[i];
                    W[13] = h2_from_bits(ev & maskR);

                    const half2_t* w = pwp + (size_t)(k1*9 + k2*3 + k3) * 9;
#pragma unroll
                    for (int co = 0; co < 3; ++co) {
                        half2_t w0 = w[co*3 + 0];
                        half2_t w1 = w[co*3 + 1];
                        half2_t w2 = w[co*3 + 2];
#pragma unroll
                        for (int j = 0; j < 12; ++j) {
                            float a = acc[co][j];
                            a = FDOT2(w0, W[j],     a);
                            a = FDOT2(w1, W[j + 1], a);
                            a = FDOT2(w2, W[j + 2], a);
                            acc[co][j] = a;
                        }
                    }
                }
            }
        }
    }

    int spos = x1 * S1 + x2 * S2 + x3 * D4 + 12 * H;
#pragma unroll
    for (int co = 0; co < 3; ++co) {
        union { float2 f2[3]; _Float16 h[12]; } u;
#pragma unroll
        for (int j = 0; j < 12; ++j) u.h[j] = (_Float16)acc[co][j];
        float2* o2 = (float2*)(dst + (b*3 + co) * (size_t)SC + spos);
#pragma unroll
        for (int q = 0; q < 3; ++q) o2[q] = u.f2[q];
    }
}

// ---------------- Stage B+C fused, lane-interleaved j-split (R2 form) --------

__global__ __launch_bounds__(256, 3) void convBC(
        const _Float16* __restrict__ t1, half2_t* pairs,
        const float* __restrict__ W1, const float* __restrict__ b1,
        const float* __restrict__ W2, const float* __restrict__ b2,
        const float* __restrict__ Wd, const float* __restrict__ bd,
        float* __restrict__ dstF32, int writeF32)
{
    int t = blockIdx.x * 256 + threadIdx.x;
    int H = t & 1;
    int s = t >> 1;
    int x3 = s % D; int r = s / D;
    int x2 = r % D; r /= D;
    int x1 = r % D; int b = r / D;
    const bool isH1 = (H != 0);

    int spos = x1 * S1 + x2 * S2 + x3 * D4;
    const int bodyOff = 12 * H;       // f16 units
    const int edgeOff = 12 - H;       // f16 units

    float t2l[3][14];
#pragma unroll
    for (int c = 0; c < 3; ++c) {
        float bb = b1[c];
        t2l[c][0]  = isH1 ? bb : 0.f;
        t2l[c][13] = isH1 ? 0.f : bb;
#pragma unroll
        for (int m = 1; m < 13; ++m) t2l[c][m] = bb;
    }

#pragma unroll 1
    for (int ci = 0; ci < 3; ++ci) {
        const _Float16* src = t1 + (b*3 + ci) * (size_t)SC;
#pragma unroll 1
        for (int k1 = 0; k1 < 3; ++k1) {
            int z1 = x1 + k1 - 1;
            if ((unsigned)z1 >= (unsigned)D) continue;
            const _Float16* src1 = src + z1 * S1;
#pragma unroll
            for (int k2 = 0; k2 < 3; ++k2) {
                int z2 = x2 + k2 - 1;
                if ((unsigned)z2 >= (unsigned)D) continue;
#pragma unroll
                for (int k3 = 0; k3 < 3; ++k3) {
                    int z3 = x3 + k3 - 1;
                    if ((unsigned)z3 >= (unsigned)D) continue;
                    const _Float16* lb = src1 + z2 * S2 + z3 * D4;
                    union { float2 f2[3]; half2_t h[6]; } Bd;
                    const float2* L2 = (const float2*)(lb + bodyOff);
                    Bd.f2[0] = L2[0]; Bd.f2[1] = L2[1]; Bd.f2[2] = L2[2];
                    _Float16 eh = lb[edgeOff];
                    float ef = (float)eh;

                    float v[14];
                    v[0]  = isH1 ? ef : 0.f;
                    v[13] = isH1 ? 0.f : ef;
#pragma unroll
                    for (int i = 0; i < 6; ++i) {
                        v[1 + 2*i] = (float)Bd.h[i].x;
                        v[2 + 2*i] = (float)Bd.h[i].y;
                    }
                    int kk = k1*9 + k2*3 + k3;
                    float wA = W1[  0 + ci*27 + kk];
                    float wB = W1[ 81 + ci*27 + kk];
                    float wC = W1[162 + ci*27 + kk];
#pragma unroll
                    for (int m = 0; m < 14; ++m) {
                        t2l[0][m] += wA * v[m];
                        t2l[1][m] += wB * v[m];
                        t2l[2][m] += wC * v[m];
                    }
                }
            }
        }
    }

    // residual source + bnd0 passthrough from pairs (this lane's 12-wide chunk)
    half2_t* p0ptr = pairs + (size_t)(b*3 + 0) * SC + spos + 12*H;
    half2_t* p1ptr = pairs + (size_t)(b*3 + 1) * SC + spos + 12*H;
    half2_t rp0[12], rp1[12];
#pragma unroll
    for (int q = 0; q < 3; ++q) {
        union { float4 f4; half2_t h[4]; } u;
        u.f4 = ((const float4*)p0ptr)[q];
        rp0[4*q+0]=u.h[0]; rp0[4*q+1]=u.h[1]; rp0[4*q+2]=u.h[2]; rp0[4*q+3]=u.h[3];
        u.f4 = ((const float4*)p1ptr)[q];
        rp1[4*q+0]=u.h[0]; rp1[4*q+1]=u.h[1]; rp1[4*q+2]=u.h[2]; rp1[4*q+3]=u.h[3];
    }

    float U[3][3][3];
#pragma unroll
    for (int co = 0; co < 3; ++co)
#pragma unroll
        for (int ci = 0; ci < 3; ++ci)
#pragma unroll
            for (int k = 0; k < 3; ++k)
                U[co][ci][k] = W2[co*9 + ci*3 + k];
    float WD[9];
#pragma unroll
    for (int i = 0; i < 9; ++i) WD[i] = Wd[i];
    float c0 = b2[0] + bd[0], c1 = b2[1] + bd[1], c2 = b2[2] + bd[2];

    float o0[12], o1[12], o2[12];
#pragma unroll
    for (int n = 0; n < 12; ++n) {
        float s0 = c0, s1 = c1, s2 = c2;
#pragma unroll
        for (int ci = 0; ci < 3; ++ci) {
            float tm = t2l[ci][n + 0];
            float tc = t2l[ci][n + 1];
            float tp = t2l[ci][n + 2];
            s0 += U[0][ci][0]*tm + U[0][ci][1]*tc + U[0][ci][2]*tp;
            s1 += U[1][ci][0]*tm + U[1][ci][1]*tc + U[1][ci][2]*tp;
            s2 += U[2][ci][0]*tm + U[2][ci][1]*tc + U[2][ci][2]*tp;
        }
        float pv0 = (float)rp0[n].x, pv1 = (float)rp0[n].y, pv2 = (float)rp1[n].x;
        s0 += WD[0]*pv0 + WD[1]*pv1 + WD[2]*pv2;
        s1 += WD[3]*pv0 + WD[4]*pv1 + WD[5]*pv2;
        s2 += WD[6]*pv0 + WD[7]*pv1 + WD[8]*pv2;
        o0[n] = s0; o1[n] = s1; o2[n] = s2;
    }

    // vectorized pair stores: plane0 = (o0,o1), plane1 = (o2, bnd0 passthrough)
    {
        union { float4 f4[3]; half2_t h[12]; } u0, u1;
#pragma unroll
        for (int n = 0; n < 12; ++n) {
            u0.h[n] = half2_t{(_Float16)o0[n], (_Float16)o1[n]};
            u1.h[n] = half2_t{(_Float16)o2[n], rp1[n].y};
        }
#pragma unroll
        for (int q = 0; q < 3; ++q) {
            ((float4*)p0ptr)[q] = u0.f4[q];
            ((float4*)p1ptr)[q] = u1.f4[q];
        }
    }

    if (writeF32) {
        float* d0 = dstF32 + (size_t)(b*3 + 0) * SC + spos + 12*H;
        float* d1 = dstF32 + (size_t)(b*3 + 1) * SC + spos + 12*H;
        float* d2 = dstF32 + (size_t)(b*3 + 2) * SC + spos + 12*H;
#pragma unroll
        for (int q = 0; q < 3; ++q) {
            ((float4*)d0)[q] = make_float4(o0[4*q], o0[4*q+1], o0[4*q+2], o0[4*q+3]);
            ((float4*)d1)[q] = make_float4(o1[4*q], o1[4*q+1], o1[4*q+2], o1[4*q+3]);
            ((float4*)d2)[q] = make_float4(o2[4*q], o2[4*q+1], o2[4*q+2], o2[4*q+3]);
        }
    }
}

extern "C" void kernel_launch(void* const* d_in, const int* in_sizes, int n_in,
                              void* d_out, int out_size, void* d_ws, size_t ws_size,
                              hipStream_t stream)
{
    const float* f   = (const float*)d_in[0];
    const float* bnd = (const float*)d_in[1];
    const float* Wg  = (const float*)d_in[2];
    const float* bg  = (const float*)d_in[3];
    const float* W1  = (const float*)d_in[4];
    const float* b1  = (const float*)d_in[5];
    const float* W2  = (const float*)d_in[6];
    const float* b2  = (const float*)d_in[7];
    const float* Wd  = (const float*)d_in[8];
    const float* bd  = (const float*)d_in[9];

    _Float16* t1h   = (_Float16*)d_ws;                   // 32 MB f16
    half2_t*  pairs = (half2_t*)(t1h + NELEM);           // 64 MB f16 pairs
    half2_t*  pw    = pairs + NPAIR_H2;                  // 11.7 KB packed weights

    pack_weights<<<dim3((2916 + 255) / 256), dim3(256), 0, stream>>>(Wg, pw);
    pack_init<<<dim3(NB * 3 * (SC / 4) / 256), dim3(256), 0, stream>>>(f, bnd, pairs);

    const int gridA  = NB * TILES;        // 1728 tiles
    const int gridBC = 2 * NS / 256;      // 1728 blocks; lane pairs share a line
    for (int l = 0; l < 4; ++l) {
        convA<<<dim3(gridA), dim3(256), 0, stream>>>(pairs, pw + l * 729, bg + l*3, t1h);
        convBC<<<dim3(gridBC), dim3(256), 0, stream>>>(
            t1h, pairs, W1 + l*243, b1 + l*3, W2 + l*27, b2 + l*3,
            Wd + l*9, bd + l*3, (float*)d_out, l == 3 ? 1 : 0);
    }
}